// Round 7
// baseline (172.486 us; speedup 1.0000x reference)
//
#include <hip/hip_runtime.h>

// Problem constants (from reference)
constexpr int   NB         = 128;          // bins per axis
constexpr int   NCELL      = NB * NB;      // 16384 cells
constexpr int   NFL        = 2 * NCELL;    // interleaved {Dx,Dy} floats = 32768
constexpr float S          = 7.8125f;      // 1000/128, exact in fp32
constexpr int   NUM_NETS   = 100000;
constexpr int   NUM_NODES  = 200000;
constexpr int   NUM_MOVABLE= 180000;
constexpr int   NUM_PINS   = 400000;
constexpr float UNIT_H_CAP = 1.5f;
constexpr float UNIT_V_CAP = 1.4f;

#define TPB   512   // net_diff block size
#define NDB   256   // net_diff blocks: 1/CU, LDS atomic pipe fully spread
#define RDB   32    // reduce blocks (8192 float4 lanes over R)

__device__ __forceinline__ float edgef(int t) { return (float)t * S; }

__device__ __forceinline__ int bin_of(float v) {
    int t = (int)floorf(v / S);
    while (edgef(t + 1) <= v) ++t;
    while (edgef(t)     >  v) --t;
    return t;
}

__device__ __forceinline__ float phi(int t, float lo, float hi) {
    return fminf(fmaxf(edgef(t), lo), hi);
}

// second difference of the clamp-ramp: <=4 nonzeros (indices >=128 dropped by
// caller; they never influence bins 0..127).
__device__ __forceinline__ int second_diff(float lo, float hi,
                                           int* idx, float* val) {
    int a = bin_of(lo);
    int b = bin_of(hi);
    int n = 0;
    idx[n] = a;
    val[n] = phi(a + 1, lo, hi) - 2.f * phi(a, lo, hi) + phi(a - 1, lo, hi);
    ++n;
    idx[n] = a + 1;
    val[n] = phi(a + 2, lo, hi) - 2.f * phi(a + 1, lo, hi) + phi(a, lo, hi);
    ++n;
    if (b > a + 1) {
        idx[n] = b;
        val[n] = phi(b + 1, lo, hi) - 2.f * phi(b, lo, hi) + phi(b - 1, lo, hi);
        ++n;
    }
    if (b > a) {
        idx[n] = b + 1;
        val[n] = phi(b + 2, lo, hi) - 2.f * phi(b + 1, lo, hi) + phi(b, lo, hi);
        ++n;
    }
    return n;
}

// K1: fused bbox gather + single-pass LDS-private scatter of BOTH maps into
// interleaved float2 cells (128 KB dynamic LDS). One net per thread.
// Also zeroes the last-block counter for K2.
__global__ __launch_bounds__(TPB) void net_diff_kernel(
    const float* __restrict__ pin_pos,
    const float* __restrict__ net_weights,
    const int*   __restrict__ nps,
    const int*   __restrict__ fnp,
    float* __restrict__ P,              // [B][NFL]
    unsigned int* __restrict__ counter) {
    extern __shared__ float Dl[];       // NFL floats = 128 KB
    const int tid = threadIdx.x;

    if (blockIdx.x == 0 && tid == 0) atomicExch(counter, 0u);

    float4* D4 = (float4*)Dl;
    for (int i = tid; i < NFL / 4; i += TPB) D4[i] = make_float4(0, 0, 0, 0);
    __syncthreads();

    for (int n = blockIdx.x * TPB + tid; n < NUM_NETS; n += gridDim.x * TPB) {
        int s = nps[n], e = nps[n + 1];
        if (e <= s) continue;
        float xmin, xmax, ymin, ymax;
        if (e - s == 4 && (s & 3) == 0) {
            int4 p4 = *(const int4*)(fnp + s);
            float x0 = pin_pos[p4.x], y0 = pin_pos[p4.x + NUM_PINS];
            float x1 = pin_pos[p4.y], y1 = pin_pos[p4.y + NUM_PINS];
            float x2 = pin_pos[p4.z], y2 = pin_pos[p4.z + NUM_PINS];
            float x3 = pin_pos[p4.w], y3 = pin_pos[p4.w + NUM_PINS];
            xmin = fminf(fminf(x0, x1), fminf(x2, x3));
            xmax = fmaxf(fmaxf(x0, x1), fmaxf(x2, x3));
            ymin = fminf(fminf(y0, y1), fminf(y2, y3));
            ymax = fmaxf(fmaxf(y0, y1), fmaxf(y2, y3));
        } else {
            xmin = 1e30f; xmax = -1e30f; ymin = 1e30f; ymax = -1e30f;
            for (int p = s; p < e; ++p) {
                int pin = fnp[p];
                float px = pin_pos[pin];
                float py = pin_pos[pin + NUM_PINS];
                xmin = fminf(xmin, px); xmax = fmaxf(xmax, px);
                ymin = fminf(ymin, py); ymax = fmaxf(ymax, py);
            }
        }
        float w  = net_weights[n];
        float dx = xmax - xmin, dy = ymax - ymin;
        float cx = (dy > 0.f) ? w / dy : 0.f;   // map_x coeff
        float cy = (dx > 0.f) ? w / dx : 0.f;   // map_y coeff
        if (cx == 0.f && cy == 0.f) continue;

        int ixs[4], iys[4];
        float vxs[4], vys[4];
        int nx = second_diff(xmin, xmax, ixs, vxs);
        int ny = second_diff(ymin, ymax, iys, vys);

        for (int i = 0; i < nx; ++i) {
            int row = ixs[i];
            float fi = vxs[i];
            if (fi == 0.f || row >= NB) continue;
            for (int j = 0; j < ny; ++j) {
                int col = iys[j];
                float t = fi * vys[j];
                if (t == 0.f || col >= NB) continue;
                int base = (row * NB + col) * 2;
                if (cx != 0.f) atomicAdd(&Dl[base],     cx * t);
                if (cy != 0.f) atomicAdd(&Dl[base + 1], cy * t);
            }
        }
    }
    __syncthreads();

    float4* Pb = (float4*)(P + (size_t)blockIdx.x * NFL);
    for (int i = tid; i < NFL / 4; i += TPB) Pb[i] = D4[i];
}

// K2: reduce partials -> R (agent-coherent), last block does 2D prefix + clip
// -> util. R published via agent-scope atomic stores/loads (cross-XCD safe).
__global__ __launch_bounds__(256) void reduce_finish_kernel(
    const float4* __restrict__ P,   // [B][NFL/4]
    float* __restrict__ R,          // [NFL] interleaved {Dx,Dy}
    float* __restrict__ Xp,         // [2][NCELL] scratch (written/read by one block)
    float* __restrict__ util,
    unsigned int* __restrict__ counter, int B) {
    constexpr int NF4 = NFL / 4;    // 8192
    int g = blockIdx.x * blockDim.x + threadIdx.x;   // 0..8191
    float4 a0 = {0,0,0,0}, a1 = {0,0,0,0}, a2 = {0,0,0,0}, a3 = {0,0,0,0};
    int b = 0;
    for (; b + 3 < B; b += 4) {
        float4 v0 = P[(size_t)(b    ) * NF4 + g];
        float4 v1 = P[(size_t)(b + 1) * NF4 + g];
        float4 v2 = P[(size_t)(b + 2) * NF4 + g];
        float4 v3 = P[(size_t)(b + 3) * NF4 + g];
        a0.x += v0.x; a0.y += v0.y; a0.z += v0.z; a0.w += v0.w;
        a1.x += v1.x; a1.y += v1.y; a1.z += v1.z; a1.w += v1.w;
        a2.x += v2.x; a2.y += v2.y; a2.z += v2.z; a2.w += v2.w;
        a3.x += v3.x; a3.y += v3.y; a3.z += v3.z; a3.w += v3.w;
    }
    for (; b < B; ++b) {
        float4 v = P[(size_t)b * NF4 + g];
        a0.x += v.x; a0.y += v.y; a0.z += v.z; a0.w += v.w;
    }
    float rx = (a0.x + a1.x) + (a2.x + a3.x);
    float ry = (a0.y + a1.y) + (a2.y + a3.y);
    float rz = (a0.z + a1.z) + (a2.z + a3.z);
    float rw = (a0.w + a1.w) + (a2.w + a3.w);
    // agent-scope publication of R
    __hip_atomic_store(&R[4 * g + 0], rx, __ATOMIC_RELAXED, __HIP_MEMORY_SCOPE_AGENT);
    __hip_atomic_store(&R[4 * g + 1], ry, __ATOMIC_RELAXED, __HIP_MEMORY_SCOPE_AGENT);
    __hip_atomic_store(&R[4 * g + 2], rz, __ATOMIC_RELAXED, __HIP_MEMORY_SCOPE_AGENT);
    __hip_atomic_store(&R[4 * g + 3], rw, __ATOMIC_RELAXED, __HIP_MEMORY_SCOPE_AGENT);
    __threadfence();

    __shared__ int last;
    __syncthreads();
    if (threadIdx.x == 0) {
        unsigned int old = atomicAdd(counter, 1u);
        last = (old == (unsigned int)gridDim.x - 1) ? 1 : 0;
    }
    __syncthreads();
    if (!last) return;
    __threadfence();   // acquire side

    // finish: x-prefix (down rows) into Xp, then y-prefix + clip -> util
    int t = threadIdx.x;
    {
        int m   = (t >= NB) ? 1 : 0;
        int col = t & (NB - 1);
        float acc = 0.f;
        #pragma unroll 4
        for (int i = 0; i < NB; ++i) {
            float v = __hip_atomic_load(&R[(i * NB + col) * 2 + m],
                                        __ATOMIC_RELAXED, __HIP_MEMORY_SCOPE_AGENT);
            acc += v;
            Xp[m * NCELL + i * NB + col] = acc;
        }
    }
    __syncthreads();
    if (t < NB) {
        constexpr float invx = 1.f / (S * S * UNIT_H_CAP);
        constexpr float invy = 1.f / (S * S * UNIT_V_CAP);
        float ax = 0.f, ay = 0.f;
        #pragma unroll 8
        for (int j = 0; j < NB; ++j) {
            int idx = t * NB + j;
            ax += Xp[idx];
            ay += Xp[NCELL + idx];
            float u = fmaxf(ax * invx, ay * invy);
            util[idx] = fminf(fmaxf(u, 0.5f), 2.0f);
        }
    }
}

// K3: per-movable-node area = sum over <=3x3 bins of ox*util*oy
__global__ __launch_bounds__(256) void node_kernel(
    const float* __restrict__ pos,
    const float* __restrict__ nsx,
    const float* __restrict__ nsy,
    const float* __restrict__ util,
    float* __restrict__ out) {
    int m = blockIdx.x * blockDim.x + threadIdx.x;
    if (m >= NUM_MOVABLE) return;
    float x  = pos[m];
    float y  = pos[NUM_NODES + m];
    float xh = x + nsx[m];
    float yh = y + nsy[m];
    int ax = max(0,      (int)floorf(x  / S) - 1);
    int bx = min(NB - 1, (int)floorf(xh / S) + 1);
    int ay = max(0,      (int)floorf(y  / S) - 1);
    int by = min(NB - 1, (int)floorf(yh / S) + 1);
    float acc = 0.f;
    for (int i = ax; i <= bx; ++i) {
        float ov = fminf(edgef(i + 1), xh) - fmaxf(edgef(i), x);
        if (ov <= 0.f) continue;
        float inner = 0.f;
        for (int j = ay; j <= by; ++j) {
            float ovy = fminf(edgef(j + 1), yh) - fmaxf(edgef(j), y);
            if (ovy > 0.f) inner += ovy * util[i * NB + j];
        }
        acc += ov * inner;
    }
    out[m] = acc;
}

extern "C" void kernel_launch(void* const* d_in, const int* in_sizes, int n_in,
                              void* d_out, int out_size, void* d_ws, size_t ws_size,
                              hipStream_t stream) {
    const float* pos      = (const float*)d_in[0];
    const float* pin_pos  = (const float*)d_in[1];
    const float* nsx      = (const float*)d_in[2];
    const float* nsy      = (const float*)d_in[3];
    const float* nw       = (const float*)d_in[4];
    const int*   npstart  = (const int*)d_in[5];
    const int*   fnp      = (const int*)d_in[6];
    float*       out      = (float*)d_out;

    // ws layout (floats): counter(4) | R[NFL] | Xp[NFL] | util[NCELL] | P[B*NFL]
    float* w    = (float*)d_ws;
    unsigned int* counter = (unsigned int*)w;  w += 4;
    float* R    = w;                           w += NFL;
    float* Xp   = w;                           w += NFL;
    float* util = w;                           w += NCELL;
    float* P    = w;

    size_t fixed = (size_t)(w - (float*)d_ws) * sizeof(float);
    int B = NDB;
    if (ws_size > fixed) {
        size_t fit = (ws_size - fixed) / ((size_t)NFL * sizeof(float));
        if ((size_t)B > fit) B = (int)fit;
    } else {
        B = 1;
    }
    if (B < 1) B = 1;

    static bool attr_done = false;
    (void)hipFuncSetAttribute((const void*)net_diff_kernel,
                              hipFuncAttributeMaxDynamicSharedMemorySize,
                              NFL * (int)sizeof(float));
    (void)attr_done;

    net_diff_kernel<<<B, TPB, NFL * sizeof(float), stream>>>(
        pin_pos, nw, npstart, fnp, P, counter);
    reduce_finish_kernel<<<RDB, 256, 0, stream>>>(
        (const float4*)P, R, Xp, util, counter, B);
    node_kernel<<<(NUM_MOVABLE + 255) / 256, 256, 0, stream>>>(
        pos, nsx, nsy, util, out);
}

// Round 8
// 157.175 us; speedup vs baseline: 1.0974x; 1.0974x over previous
//
#include <hip/hip_runtime.h>

// Problem constants (from reference)
constexpr int   NB         = 128;          // bins per axis
constexpr int   NCELL      = NB * NB;      // 16384 cells
constexpr int   NFL        = 2 * NCELL;    // interleaved {Dx,Dy} floats = 32768
constexpr float S          = 7.8125f;      // 1000/128, exact in fp32
constexpr int   NUM_NETS   = 100000;
constexpr int   NUM_NODES  = 200000;
constexpr int   NUM_MOVABLE= 180000;
constexpr int   NUM_PINS   = 400000;
constexpr float UNIT_H_CAP = 1.5f;
constexpr float UNIT_V_CAP = 1.4f;

#define TPB    512   // net_diff block size
#define NDB    256   // net_diff blocks: 1/CU, LDS atomic pipe fully spread
#define NCHUNK 8     // reduce b-parallelism (grid 32 x 8 = 65536 threads)

__device__ __forceinline__ float edgef(int t) { return (float)t * S; }

__device__ __forceinline__ int bin_of(float v) {
    int t = (int)floorf(v / S);
    while (edgef(t + 1) <= v) ++t;
    while (edgef(t)     >  v) --t;
    return t;
}

__device__ __forceinline__ float phi(int t, float lo, float hi) {
    return fminf(fmaxf(edgef(t), lo), hi);
}

// second difference of the clamp-ramp: <=4 nonzeros (indices >=128 dropped by
// caller; they never influence bins 0..127).
__device__ __forceinline__ int second_diff(float lo, float hi,
                                           int* idx, float* val) {
    int a = bin_of(lo);
    int b = bin_of(hi);
    int n = 0;
    idx[n] = a;
    val[n] = phi(a + 1, lo, hi) - 2.f * phi(a, lo, hi) + phi(a - 1, lo, hi);
    ++n;
    idx[n] = a + 1;
    val[n] = phi(a + 2, lo, hi) - 2.f * phi(a + 1, lo, hi) + phi(a, lo, hi);
    ++n;
    if (b > a + 1) {
        idx[n] = b;
        val[n] = phi(b + 1, lo, hi) - 2.f * phi(b, lo, hi) + phi(b - 1, lo, hi);
        ++n;
    }
    if (b > a) {
        idx[n] = b + 1;
        val[n] = phi(b + 2, lo, hi) - 2.f * phi(b + 1, lo, hi) + phi(b, lo, hi);
        ++n;
    }
    return n;
}

// K1: fused bbox gather + single-pass LDS-private scatter of BOTH maps into
// interleaved float2 cells (128 KB dynamic LDS). One net per thread.
// LDS-atomic-pipe bound: ~3.2M lane-ops / 256 blocks * ~4cyc => ~21 us floor.
__global__ __launch_bounds__(TPB) void net_diff_kernel(
    const float* __restrict__ pin_pos,
    const float* __restrict__ net_weights,
    const int*   __restrict__ nps,
    const int*   __restrict__ fnp,
    float* __restrict__ P) {            // [B][NFL]
    extern __shared__ float Dl[];       // NFL floats = 128 KB
    const int tid = threadIdx.x;

    float4* D4 = (float4*)Dl;
    for (int i = tid; i < NFL / 4; i += TPB) D4[i] = make_float4(0, 0, 0, 0);
    __syncthreads();

    for (int n = blockIdx.x * TPB + tid; n < NUM_NETS; n += gridDim.x * TPB) {
        int s = nps[n], e = nps[n + 1];
        if (e <= s) continue;
        float xmin, xmax, ymin, ymax;
        if (e - s == 4 && (s & 3) == 0) {
            int4 p4 = *(const int4*)(fnp + s);
            float x0 = pin_pos[p4.x], y0 = pin_pos[p4.x + NUM_PINS];
            float x1 = pin_pos[p4.y], y1 = pin_pos[p4.y + NUM_PINS];
            float x2 = pin_pos[p4.z], y2 = pin_pos[p4.z + NUM_PINS];
            float x3 = pin_pos[p4.w], y3 = pin_pos[p4.w + NUM_PINS];
            xmin = fminf(fminf(x0, x1), fminf(x2, x3));
            xmax = fmaxf(fmaxf(x0, x1), fmaxf(x2, x3));
            ymin = fminf(fminf(y0, y1), fminf(y2, y3));
            ymax = fmaxf(fmaxf(y0, y1), fmaxf(y2, y3));
        } else {
            xmin = 1e30f; xmax = -1e30f; ymin = 1e30f; ymax = -1e30f;
            for (int p = s; p < e; ++p) {
                int pin = fnp[p];
                float px = pin_pos[pin];
                float py = pin_pos[pin + NUM_PINS];
                xmin = fminf(xmin, px); xmax = fmaxf(xmax, px);
                ymin = fminf(ymin, py); ymax = fmaxf(ymax, py);
            }
        }
        float w  = net_weights[n];
        float dx = xmax - xmin, dy = ymax - ymin;
        float cx = (dy > 0.f) ? w / dy : 0.f;   // map_x coeff
        float cy = (dx > 0.f) ? w / dx : 0.f;   // map_y coeff
        if (cx == 0.f && cy == 0.f) continue;

        int ixs[4], iys[4];
        float vxs[4], vys[4];
        int nx = second_diff(xmin, xmax, ixs, vxs);
        int ny = second_diff(ymin, ymax, iys, vys);

        for (int i = 0; i < nx; ++i) {
            int row = ixs[i];
            float fi = vxs[i];
            if (fi == 0.f || row >= NB) continue;
            for (int j = 0; j < ny; ++j) {
                int col = iys[j];
                float t = fi * vys[j];
                if (t == 0.f || col >= NB) continue;
                int base = (row * NB + col) * 2;
                if (cx != 0.f) atomicAdd(&Dl[base],     cx * t);
                if (cy != 0.f) atomicAdd(&Dl[base + 1], cy * t);
            }
        }
    }
    __syncthreads();

    float4* Pb = (float4*)(P + (size_t)blockIdx.x * NFL);
    for (int i = tid; i < NFL / 4; i += TPB) Pb[i] = D4[i];
}

// K2: chunked reduce: Rc[chunk][NFL] = sum of partial slice. 65536 threads.
__global__ __launch_bounds__(256) void reduce_kernel(
    const float4* __restrict__ P,   // [B][NFL/4]
    float4* __restrict__ Rc,        // [NCHUNK][NFL/4]
    int B) {
    constexpr int NF4 = NFL / 4;    // 8192
    int g = blockIdx.x * blockDim.x + threadIdx.x;   // 0..8191
    int chunk = blockIdx.y;
    int per = (B + NCHUNK - 1) / NCHUNK;
    int b0 = chunk * per;
    int b1 = min(b0 + per, B);
    float4 a0 = {0,0,0,0}, a1 = {0,0,0,0}, a2 = {0,0,0,0}, a3 = {0,0,0,0};
    int b = b0;
    for (; b + 3 < b1; b += 4) {
        float4 v0 = P[(size_t)(b    ) * NF4 + g];
        float4 v1 = P[(size_t)(b + 1) * NF4 + g];
        float4 v2 = P[(size_t)(b + 2) * NF4 + g];
        float4 v3 = P[(size_t)(b + 3) * NF4 + g];
        a0.x += v0.x; a0.y += v0.y; a0.z += v0.z; a0.w += v0.w;
        a1.x += v1.x; a1.y += v1.y; a1.z += v1.z; a1.w += v1.w;
        a2.x += v2.x; a2.y += v2.y; a2.z += v2.z; a2.w += v2.w;
        a3.x += v3.x; a3.y += v3.y; a3.z += v3.z; a3.w += v3.w;
    }
    for (; b < b1; ++b) {
        float4 v = P[(size_t)b * NF4 + g];
        a0.x += v.x; a0.y += v.y; a0.z += v.z; a0.w += v.w;
    }
    float4 r;
    r.x = (a0.x + a1.x) + (a2.x + a3.x);
    r.y = (a0.y + a1.y) + (a2.y + a3.y);
    r.z = (a0.z + a1.z) + (a2.z + a3.z);
    r.w = (a0.w + a1.w) + (a2.w + a3.w);
    Rc[(size_t)chunk * NF4 + g] = r;
}

// K3: single-block finish: sum NCHUNK chunk maps + x-prefix into Xp, barrier,
// y-prefix + clip -> util. Launch boundary provides coherence for Rc.
__global__ __launch_bounds__(256) void finish_kernel(
    const float* __restrict__ Rc,    // [NCHUNK][NFL] interleaved {Dx,Dy}
    float* __restrict__ Xp,          // [2][NCELL] scratch
    float* __restrict__ util) {
    int t = threadIdx.x;
    int m   = (t >= NB) ? 1 : 0;
    int col = t & (NB - 1);
    float acc = 0.f;
    #pragma unroll 4
    for (int i = 0; i < NB; ++i) {
        int idx = (i * NB + col) * 2 + m;
        float v = 0.f;
        #pragma unroll
        for (int c = 0; c < NCHUNK; ++c)
            v += Rc[(size_t)c * NFL + idx];
        acc += v;
        Xp[m * NCELL + i * NB + col] = acc;
    }
    __syncthreads();
    if (t < NB) {
        constexpr float invx = 1.f / (S * S * UNIT_H_CAP);
        constexpr float invy = 1.f / (S * S * UNIT_V_CAP);
        float ax = 0.f, ay = 0.f;
        #pragma unroll 8
        for (int j = 0; j < NB; ++j) {
            int idx = t * NB + j;
            ax += Xp[idx];
            ay += Xp[NCELL + idx];
            float u = fmaxf(ax * invx, ay * invy);
            util[idx] = fminf(fmaxf(u, 0.5f), 2.0f);
        }
    }
}

// K4: per-movable-node area = sum over <=3x3 bins of ox*util*oy
__global__ __launch_bounds__(256) void node_kernel(
    const float* __restrict__ pos,
    const float* __restrict__ nsx,
    const float* __restrict__ nsy,
    const float* __restrict__ util,
    float* __restrict__ out) {
    int m = blockIdx.x * blockDim.x + threadIdx.x;
    if (m >= NUM_MOVABLE) return;
    float x  = pos[m];
    float y  = pos[NUM_NODES + m];
    float xh = x + nsx[m];
    float yh = y + nsy[m];
    int ax = max(0,      (int)floorf(x  / S) - 1);
    int bx = min(NB - 1, (int)floorf(xh / S) + 1);
    int ay = max(0,      (int)floorf(y  / S) - 1);
    int by = min(NB - 1, (int)floorf(yh / S) + 1);
    float acc = 0.f;
    for (int i = ax; i <= bx; ++i) {
        float ov = fminf(edgef(i + 1), xh) - fmaxf(edgef(i), x);
        if (ov <= 0.f) continue;
        float inner = 0.f;
        for (int j = ay; j <= by; ++j) {
            float ovy = fminf(edgef(j + 1), yh) - fmaxf(edgef(j), y);
            if (ovy > 0.f) inner += ovy * util[i * NB + j];
        }
        acc += ov * inner;
    }
    out[m] = acc;
}

extern "C" void kernel_launch(void* const* d_in, const int* in_sizes, int n_in,
                              void* d_out, int out_size, void* d_ws, size_t ws_size,
                              hipStream_t stream) {
    const float* pos      = (const float*)d_in[0];
    const float* pin_pos  = (const float*)d_in[1];
    const float* nsx      = (const float*)d_in[2];
    const float* nsy      = (const float*)d_in[3];
    const float* nw       = (const float*)d_in[4];
    const int*   npstart  = (const int*)d_in[5];
    const int*   fnp      = (const int*)d_in[6];
    float*       out      = (float*)d_out;

    // ws layout (floats): Rc[NCHUNK*NFL] | Xp[NFL] | util[NCELL] | P[B*NFL]
    float* w    = (float*)d_ws;
    float* Rc   = w;                           w += NCHUNK * NFL;
    float* Xp   = w;                           w += NFL;
    float* util = w;                           w += NCELL;
    float* P    = w;

    size_t fixed = (size_t)(w - (float*)d_ws) * sizeof(float);
    int B = NDB;
    if (ws_size > fixed) {
        size_t fit = (ws_size - fixed) / ((size_t)NFL * sizeof(float));
        if ((size_t)B > fit) B = (int)fit;
    } else {
        B = 1;
    }
    if (B < 1) B = 1;

    (void)hipFuncSetAttribute((const void*)net_diff_kernel,
                              hipFuncAttributeMaxDynamicSharedMemorySize,
                              NFL * (int)sizeof(float));

    net_diff_kernel<<<B, TPB, NFL * sizeof(float), stream>>>(
        pin_pos, nw, npstart, fnp, P);
    {
        dim3 g(NFL / 4 / 256, NCHUNK);   // 32 x 8 blocks
        reduce_kernel<<<g, 256, 0, stream>>>(
            (const float4*)P, (float4*)Rc, B);
    }
    finish_kernel<<<1, 256, 0, stream>>>(Rc, Xp, util);
    node_kernel<<<(NUM_MOVABLE + 255) / 256, 256, 0, stream>>>(
        pos, nsx, nsy, util, out);
}

// Round 9
// 117.547 us; speedup vs baseline: 1.4674x; 1.3371x over previous
//
#include <hip/hip_runtime.h>

// Problem constants (from reference)
constexpr int   NB         = 128;          // bins per axis
constexpr int   NCELL      = NB * NB;      // 16384 cells
constexpr int   NFL        = 2 * NCELL;    // interleaved {Dx,Dy} floats = 32768
constexpr float S          = 7.8125f;      // 1000/128, exact in fp32
constexpr int   NUM_NETS   = 100000;
constexpr int   NUM_NODES  = 200000;
constexpr int   NUM_MOVABLE= 180000;
constexpr int   NUM_PINS   = 400000;
constexpr float UNIT_H_CAP = 1.5f;
constexpr float UNIT_V_CAP = 1.4f;

#define TPB    512   // net_diff block size
#define NDB    256   // net_diff blocks: 1/CU, LDS atomic pipe fully spread
#define NCHUNK 8     // reduce b-parallelism (grid 32 x 8 = 65536 threads)

__device__ __forceinline__ float edgef(int t) { return (float)t * S; }

__device__ __forceinline__ int bin_of(float v) {
    int t = (int)floorf(v / S);
    while (edgef(t + 1) <= v) ++t;
    while (edgef(t)     >  v) --t;
    return t;
}

__device__ __forceinline__ float phi(int t, float lo, float hi) {
    return fminf(fmaxf(edgef(t), lo), hi);
}

// second difference of the clamp-ramp: <=4 nonzeros (indices >=128 dropped by
// caller; they never influence bins 0..127).
__device__ __forceinline__ int second_diff(float lo, float hi,
                                           int* idx, float* val) {
    int a = bin_of(lo);
    int b = bin_of(hi);
    int n = 0;
    idx[n] = a;
    val[n] = phi(a + 1, lo, hi) - 2.f * phi(a, lo, hi) + phi(a - 1, lo, hi);
    ++n;
    idx[n] = a + 1;
    val[n] = phi(a + 2, lo, hi) - 2.f * phi(a + 1, lo, hi) + phi(a, lo, hi);
    ++n;
    if (b > a + 1) {
        idx[n] = b;
        val[n] = phi(b + 1, lo, hi) - 2.f * phi(b, lo, hi) + phi(b - 1, lo, hi);
        ++n;
    }
    if (b > a) {
        idx[n] = b + 1;
        val[n] = phi(b + 2, lo, hi) - 2.f * phi(b + 1, lo, hi) + phi(b, lo, hi);
        ++n;
    }
    return n;
}

// K1: fused bbox gather + single-pass LDS-private scatter of BOTH maps into
// interleaved float2 cells (128 KB dynamic LDS). One net per thread.
// LDS-atomic-pipe bound: ~3.2M lane-ops / 256 blocks * ~4cyc => ~21 us floor.
__global__ __launch_bounds__(TPB) void net_diff_kernel(
    const float* __restrict__ pin_pos,
    const float* __restrict__ net_weights,
    const int*   __restrict__ nps,
    const int*   __restrict__ fnp,
    float* __restrict__ P) {            // [B][NFL]
    extern __shared__ float Dl[];       // NFL floats = 128 KB
    const int tid = threadIdx.x;

    float4* D4 = (float4*)Dl;
    for (int i = tid; i < NFL / 4; i += TPB) D4[i] = make_float4(0, 0, 0, 0);
    __syncthreads();

    for (int n = blockIdx.x * TPB + tid; n < NUM_NETS; n += gridDim.x * TPB) {
        int s = nps[n], e = nps[n + 1];
        if (e <= s) continue;
        float xmin, xmax, ymin, ymax;
        if (e - s == 4 && (s & 3) == 0) {
            int4 p4 = *(const int4*)(fnp + s);
            float x0 = pin_pos[p4.x], y0 = pin_pos[p4.x + NUM_PINS];
            float x1 = pin_pos[p4.y], y1 = pin_pos[p4.y + NUM_PINS];
            float x2 = pin_pos[p4.z], y2 = pin_pos[p4.z + NUM_PINS];
            float x3 = pin_pos[p4.w], y3 = pin_pos[p4.w + NUM_PINS];
            xmin = fminf(fminf(x0, x1), fminf(x2, x3));
            xmax = fmaxf(fmaxf(x0, x1), fmaxf(x2, x3));
            ymin = fminf(fminf(y0, y1), fminf(y2, y3));
            ymax = fmaxf(fmaxf(y0, y1), fmaxf(y2, y3));
        } else {
            xmin = 1e30f; xmax = -1e30f; ymin = 1e30f; ymax = -1e30f;
            for (int p = s; p < e; ++p) {
                int pin = fnp[p];
                float px = pin_pos[pin];
                float py = pin_pos[pin + NUM_PINS];
                xmin = fminf(xmin, px); xmax = fmaxf(xmax, px);
                ymin = fminf(ymin, py); ymax = fmaxf(ymax, py);
            }
        }
        float w  = net_weights[n];
        float dx = xmax - xmin, dy = ymax - ymin;
        float cx = (dy > 0.f) ? w / dy : 0.f;   // map_x coeff
        float cy = (dx > 0.f) ? w / dx : 0.f;   // map_y coeff
        if (cx == 0.f && cy == 0.f) continue;

        int ixs[4], iys[4];
        float vxs[4], vys[4];
        int nx = second_diff(xmin, xmax, ixs, vxs);
        int ny = second_diff(ymin, ymax, iys, vys);

        for (int i = 0; i < nx; ++i) {
            int row = ixs[i];
            float fi = vxs[i];
            if (fi == 0.f || row >= NB) continue;
            for (int j = 0; j < ny; ++j) {
                int col = iys[j];
                float t = fi * vys[j];
                if (t == 0.f || col >= NB) continue;
                int base = (row * NB + col) * 2;
                if (cx != 0.f) atomicAdd(&Dl[base],     cx * t);
                if (cy != 0.f) atomicAdd(&Dl[base + 1], cy * t);
            }
        }
    }
    __syncthreads();

    float4* Pb = (float4*)(P + (size_t)blockIdx.x * NFL);
    for (int i = tid; i < NFL / 4; i += TPB) Pb[i] = D4[i];
}

// K2: chunked reduce: Rc[chunk][NFL] = sum of partial slice. 65536 threads.
__global__ __launch_bounds__(256) void reduce_kernel(
    const float4* __restrict__ P,   // [B][NFL/4]
    float4* __restrict__ Rc,        // [NCHUNK][NFL/4]
    int B) {
    constexpr int NF4 = NFL / 4;    // 8192
    int g = blockIdx.x * blockDim.x + threadIdx.x;   // 0..8191
    int chunk = blockIdx.y;
    int per = (B + NCHUNK - 1) / NCHUNK;
    int b0 = chunk * per;
    int b1 = min(b0 + per, B);
    float4 a0 = {0,0,0,0}, a1 = {0,0,0,0}, a2 = {0,0,0,0}, a3 = {0,0,0,0};
    int b = b0;
    for (; b + 3 < b1; b += 4) {
        float4 v0 = P[(size_t)(b    ) * NF4 + g];
        float4 v1 = P[(size_t)(b + 1) * NF4 + g];
        float4 v2 = P[(size_t)(b + 2) * NF4 + g];
        float4 v3 = P[(size_t)(b + 3) * NF4 + g];
        a0.x += v0.x; a0.y += v0.y; a0.z += v0.z; a0.w += v0.w;
        a1.x += v1.x; a1.y += v1.y; a1.z += v1.z; a1.w += v1.w;
        a2.x += v2.x; a2.y += v2.y; a2.z += v2.z; a2.w += v2.w;
        a3.x += v3.x; a3.y += v3.y; a3.z += v3.z; a3.w += v3.w;
    }
    for (; b < b1; ++b) {
        float4 v = P[(size_t)b * NF4 + g];
        a0.x += v.x; a0.y += v.y; a0.z += v.z; a0.w += v.w;
    }
    float4 r;
    r.x = (a0.x + a1.x) + (a2.x + a3.x);
    r.y = (a0.y + a1.y) + (a2.y + a3.y);
    r.z = (a0.z + a1.z) + (a2.z + a3.z);
    r.w = (a0.w + a1.w) + (a2.w + a3.w);
    Rc[(size_t)chunk * NF4 + g] = r;
}

// K3: x-prefix. One block per y-column; thread t = x-row. Sums the 8 chunk
// maps (float2 = both maps at once), LDS Hillis-Steele scan over 128 rows.
__global__ __launch_bounds__(NB) void scan_x_kernel(
    const float2* __restrict__ Rc,   // [NCHUNK][NCELL] float2 cells
    float2* __restrict__ Xp) {       // [NCELL] float2, x-prefixed
    __shared__ float2 sm[NB];
    int col = blockIdx.x;
    int t = threadIdx.x;
    int idx = t * NB + col;
    float2 v = make_float2(0.f, 0.f);
    #pragma unroll
    for (int c = 0; c < NCHUNK; ++c) {
        float2 u = Rc[(size_t)c * NCELL + idx];
        v.x += u.x; v.y += u.y;
    }
    sm[t] = v;
    __syncthreads();
    #pragma unroll
    for (int off = 1; off < NB; off <<= 1) {
        float2 cur = sm[t];
        float2 add = (t >= off) ? sm[t - off] : make_float2(0.f, 0.f);
        __syncthreads();
        cur.x += add.x; cur.y += add.y;
        sm[t] = cur;
        __syncthreads();
    }
    Xp[idx] = sm[t];
}

// K4: y-prefix + clip -> util. One block per x-row; coalesced float2 loads.
__global__ __launch_bounds__(NB) void scan_y_kernel(
    const float2* __restrict__ Xp,   // [NCELL] float2
    float* __restrict__ util) {
    __shared__ float2 sm[NB];
    int row = blockIdx.x;
    int t = threadIdx.x;
    sm[t] = Xp[row * NB + t];
    __syncthreads();
    #pragma unroll
    for (int off = 1; off < NB; off <<= 1) {
        float2 cur = sm[t];
        float2 add = (t >= off) ? sm[t - off] : make_float2(0.f, 0.f);
        __syncthreads();
        cur.x += add.x; cur.y += add.y;
        sm[t] = cur;
        __syncthreads();
    }
    constexpr float invx = 1.f / (S * S * UNIT_H_CAP);
    constexpr float invy = 1.f / (S * S * UNIT_V_CAP);
    float2 r = sm[t];
    float u = fmaxf(r.x * invx, r.y * invy);
    util[row * NB + t] = fminf(fmaxf(u, 0.5f), 2.0f);
}

// K5: per-movable-node area = sum over <=3x3 bins of ox*util*oy
__global__ __launch_bounds__(256) void node_kernel(
    const float* __restrict__ pos,
    const float* __restrict__ nsx,
    const float* __restrict__ nsy,
    const float* __restrict__ util,
    float* __restrict__ out) {
    int m = blockIdx.x * blockDim.x + threadIdx.x;
    if (m >= NUM_MOVABLE) return;
    float x  = pos[m];
    float y  = pos[NUM_NODES + m];
    float xh = x + nsx[m];
    float yh = y + nsy[m];
    int ax = max(0,      (int)floorf(x  / S) - 1);
    int bx = min(NB - 1, (int)floorf(xh / S) + 1);
    int ay = max(0,      (int)floorf(y  / S) - 1);
    int by = min(NB - 1, (int)floorf(yh / S) + 1);
    float acc = 0.f;
    for (int i = ax; i <= bx; ++i) {
        float ov = fminf(edgef(i + 1), xh) - fmaxf(edgef(i), x);
        if (ov <= 0.f) continue;
        float inner = 0.f;
        for (int j = ay; j <= by; ++j) {
            float ovy = fminf(edgef(j + 1), yh) - fmaxf(edgef(j), y);
            if (ovy > 0.f) inner += ovy * util[i * NB + j];
        }
        acc += ov * inner;
    }
    out[m] = acc;
}

extern "C" void kernel_launch(void* const* d_in, const int* in_sizes, int n_in,
                              void* d_out, int out_size, void* d_ws, size_t ws_size,
                              hipStream_t stream) {
    const float* pos      = (const float*)d_in[0];
    const float* pin_pos  = (const float*)d_in[1];
    const float* nsx      = (const float*)d_in[2];
    const float* nsy      = (const float*)d_in[3];
    const float* nw       = (const float*)d_in[4];
    const int*   npstart  = (const int*)d_in[5];
    const int*   fnp      = (const int*)d_in[6];
    float*       out      = (float*)d_out;

    // ws layout (floats): Rc[NCHUNK*NFL] | Xp[NFL] | util[NCELL] | P[B*NFL]
    float* w    = (float*)d_ws;
    float* Rc   = w;                           w += NCHUNK * NFL;
    float* Xp   = w;                           w += NFL;
    float* util = w;                           w += NCELL;
    float* P    = w;

    size_t fixed = (size_t)(w - (float*)d_ws) * sizeof(float);
    int B = NDB;
    if (ws_size > fixed) {
        size_t fit = (ws_size - fixed) / ((size_t)NFL * sizeof(float));
        if ((size_t)B > fit) B = (int)fit;
    } else {
        B = 1;
    }
    if (B < 1) B = 1;

    (void)hipFuncSetAttribute((const void*)net_diff_kernel,
                              hipFuncAttributeMaxDynamicSharedMemorySize,
                              NFL * (int)sizeof(float));

    net_diff_kernel<<<B, TPB, NFL * sizeof(float), stream>>>(
        pin_pos, nw, npstart, fnp, P);
    {
        dim3 g(NFL / 4 / 256, NCHUNK);   // 32 x 8 blocks
        reduce_kernel<<<g, 256, 0, stream>>>(
            (const float4*)P, (float4*)Rc, B);
    }
    scan_x_kernel<<<NB, NB, 0, stream>>>((const float2*)Rc, (float2*)Xp);
    scan_y_kernel<<<NB, NB, 0, stream>>>((const float2*)Xp, util);
    node_kernel<<<(NUM_MOVABLE + 255) / 256, 256, 0, stream>>>(
        pos, nsx, nsy, util, out);
}

// Round 10
// 115.579 us; speedup vs baseline: 1.4924x; 1.0170x over previous
//
#include <hip/hip_runtime.h>

// Problem constants (from reference)
constexpr int   NB         = 128;          // bins per axis
constexpr int   NCELL      = NB * NB;      // 16384 cells
constexpr int   NFL        = 2 * NCELL;    // [Dx | Dy] floats = 32768 (de-interleaved)
constexpr float S          = 7.8125f;      // 1000/128, exact in fp32
constexpr int   NUM_NETS   = 100000;
constexpr int   NUM_NODES  = 200000;
constexpr int   NUM_MOVABLE= 180000;
constexpr int   NUM_PINS   = 400000;
constexpr float UNIT_H_CAP = 1.5f;
constexpr float UNIT_V_CAP = 1.4f;

#define TPB    512   // net_diff block size
#define NDB    256   // net_diff blocks: 1/CU, LDS atomic pipe fully spread
#define NCHUNK 8     // reduce b-parallelism (grid 32 x 8 = 65536 threads)

__device__ __forceinline__ float edgef(int t) { return (float)t * S; }

__device__ __forceinline__ int bin_of(float v) {
    int t = (int)floorf(v / S);
    while (edgef(t + 1) <= v) ++t;
    while (edgef(t)     >  v) --t;
    return t;
}

__device__ __forceinline__ float phi(int t, float lo, float hi) {
    return fminf(fmaxf(edgef(t), lo), hi);
}

// second difference of the clamp-ramp: <=4 nonzeros (indices >=128 dropped by
// caller; they never influence bins 0..127).
__device__ __forceinline__ int second_diff(float lo, float hi,
                                           int* idx, float* val) {
    int a = bin_of(lo);
    int b = bin_of(hi);
    int n = 0;
    idx[n] = a;
    val[n] = phi(a + 1, lo, hi) - 2.f * phi(a, lo, hi) + phi(a - 1, lo, hi);
    ++n;
    idx[n] = a + 1;
    val[n] = phi(a + 2, lo, hi) - 2.f * phi(a + 1, lo, hi) + phi(a, lo, hi);
    ++n;
    if (b > a + 1) {
        idx[n] = b;
        val[n] = phi(b + 1, lo, hi) - 2.f * phi(b, lo, hi) + phi(b - 1, lo, hi);
        ++n;
    }
    if (b > a) {
        idx[n] = b + 1;
        val[n] = phi(b + 2, lo, hi) - 2.f * phi(b + 1, lo, hi) + phi(b, lo, hi);
        ++n;
    }
    return n;
}

// K1: fused bbox gather + single-pass LDS-private scatter into DE-INTERLEAVED
// Dx/Dy halves (128 KB dynamic LDS). Nets assigned round-robin mod gridDim so
// every block carries ~391 nets (balanced atomic load). Bank of cell (r,c) is
// c%32 in each half -> full 32-bank spread per atomic wave-op.
__global__ __launch_bounds__(TPB) void net_diff_kernel(
    const float* __restrict__ pin_pos,
    const float* __restrict__ net_weights,
    const int*   __restrict__ nps,
    const int*   __restrict__ fnp,
    float* __restrict__ P) {            // [B][NFL]
    extern __shared__ float Dl[];       // [Dx NCELL | Dy NCELL]
    const int tid = threadIdx.x;
    const int G   = gridDim.x;

    float4* D4 = (float4*)Dl;
    for (int i = tid; i < NFL / 4; i += TPB) D4[i] = make_float4(0, 0, 0, 0);
    __syncthreads();

    // net n handled iff n % G == blockIdx.x; thread t takes k = t, t+TPB, ...
    for (int k = tid; ; k += TPB) {
        long long nn = (long long)blockIdx.x + (long long)G * k;
        if (nn >= NUM_NETS) break;
        int n = (int)nn;
        int s = nps[n], e = nps[n + 1];
        if (e <= s) continue;
        float xmin, xmax, ymin, ymax;
        if (e - s == 4 && (s & 3) == 0) {
            int4 p4 = *(const int4*)(fnp + s);
            float x0 = pin_pos[p4.x], y0 = pin_pos[p4.x + NUM_PINS];
            float x1 = pin_pos[p4.y], y1 = pin_pos[p4.y + NUM_PINS];
            float x2 = pin_pos[p4.z], y2 = pin_pos[p4.z + NUM_PINS];
            float x3 = pin_pos[p4.w], y3 = pin_pos[p4.w + NUM_PINS];
            xmin = fminf(fminf(x0, x1), fminf(x2, x3));
            xmax = fmaxf(fmaxf(x0, x1), fmaxf(x2, x3));
            ymin = fminf(fminf(y0, y1), fminf(y2, y3));
            ymax = fmaxf(fmaxf(y0, y1), fmaxf(y2, y3));
        } else {
            xmin = 1e30f; xmax = -1e30f; ymin = 1e30f; ymax = -1e30f;
            for (int p = s; p < e; ++p) {
                int pin = fnp[p];
                float px = pin_pos[pin];
                float py = pin_pos[pin + NUM_PINS];
                xmin = fminf(xmin, px); xmax = fmaxf(xmax, px);
                ymin = fminf(ymin, py); ymax = fmaxf(ymax, py);
            }
        }
        float w  = net_weights[n];
        float dx = xmax - xmin, dy = ymax - ymin;
        float cx = (dy > 0.f) ? w / dy : 0.f;   // map_x coeff
        float cy = (dx > 0.f) ? w / dx : 0.f;   // map_y coeff
        if (cx == 0.f && cy == 0.f) continue;

        int ixs[4], iys[4];
        float vxs[4], vys[4];
        int nx = second_diff(xmin, xmax, ixs, vxs);
        int ny = second_diff(ymin, ymax, iys, vys);

        for (int i = 0; i < nx; ++i) {
            int row = ixs[i];
            float fi = vxs[i];
            if (fi == 0.f || row >= NB) continue;
            for (int j = 0; j < ny; ++j) {
                int col = iys[j];
                float t = fi * vys[j];
                if (t == 0.f || col >= NB) continue;
                int cell = row * NB + col;
                if (cx != 0.f) atomicAdd(&Dl[cell],         cx * t);
                if (cy != 0.f) atomicAdd(&Dl[NCELL + cell], cy * t);
            }
        }
    }
    __syncthreads();

    float4* Pb = (float4*)(P + (size_t)blockIdx.x * NFL);
    for (int i = tid; i < NFL / 4; i += TPB) Pb[i] = D4[i];
}

// K2: chunked reduce: Rc[chunk][NFL] = sum of partial slice. 65536 threads.
__global__ __launch_bounds__(256) void reduce_kernel(
    const float4* __restrict__ P,   // [B][NFL/4]
    float4* __restrict__ Rc,        // [NCHUNK][NFL/4]
    int B) {
    constexpr int NF4 = NFL / 4;    // 8192
    int g = blockIdx.x * blockDim.x + threadIdx.x;   // 0..8191
    int chunk = blockIdx.y;
    int per = (B + NCHUNK - 1) / NCHUNK;
    int b0 = chunk * per;
    int b1 = min(b0 + per, B);
    float4 a0 = {0,0,0,0}, a1 = {0,0,0,0}, a2 = {0,0,0,0}, a3 = {0,0,0,0};
    int b = b0;
    for (; b + 3 < b1; b += 4) {
        float4 v0 = P[(size_t)(b    ) * NF4 + g];
        float4 v1 = P[(size_t)(b + 1) * NF4 + g];
        float4 v2 = P[(size_t)(b + 2) * NF4 + g];
        float4 v3 = P[(size_t)(b + 3) * NF4 + g];
        a0.x += v0.x; a0.y += v0.y; a0.z += v0.z; a0.w += v0.w;
        a1.x += v1.x; a1.y += v1.y; a1.z += v1.z; a1.w += v1.w;
        a2.x += v2.x; a2.y += v2.y; a2.z += v2.z; a2.w += v2.w;
        a3.x += v3.x; a3.y += v3.y; a3.z += v3.z; a3.w += v3.w;
    }
    for (; b < b1; ++b) {
        float4 v = P[(size_t)b * NF4 + g];
        a0.x += v.x; a0.y += v.y; a0.z += v.z; a0.w += v.w;
    }
    float4 r;
    r.x = (a0.x + a1.x) + (a2.x + a3.x);
    r.y = (a0.y + a1.y) + (a2.y + a3.y);
    r.z = (a0.z + a1.z) + (a2.z + a3.z);
    r.w = (a0.w + a1.w) + (a2.w + a3.w);
    Rc[(size_t)chunk * NF4 + g] = r;
}

// K3: x-prefix. One block per y-column; thread t = x-row. Sums the 8 chunk
// maps for both (de-interleaved) halves, LDS Hillis-Steele scan over 128 rows.
__global__ __launch_bounds__(NB) void scan_x_kernel(
    const float* __restrict__ Rc,    // [NCHUNK][2][NCELL]
    float2* __restrict__ Xp) {       // [NCELL] float2, x-prefixed
    __shared__ float2 sm[NB];
    int col = blockIdx.x;
    int t = threadIdx.x;
    int idx = t * NB + col;
    float2 v = make_float2(0.f, 0.f);
    #pragma unroll
    for (int c = 0; c < NCHUNK; ++c) {
        v.x += Rc[(size_t)c * NFL + idx];
        v.y += Rc[(size_t)c * NFL + NCELL + idx];
    }
    sm[t] = v;
    __syncthreads();
    #pragma unroll
    for (int off = 1; off < NB; off <<= 1) {
        float2 cur = sm[t];
        float2 add = (t >= off) ? sm[t - off] : make_float2(0.f, 0.f);
        __syncthreads();
        cur.x += add.x; cur.y += add.y;
        sm[t] = cur;
        __syncthreads();
    }
    Xp[idx] = sm[t];
}

// K4: y-prefix + clip -> util. One block per x-row; coalesced float2 loads.
__global__ __launch_bounds__(NB) void scan_y_kernel(
    const float2* __restrict__ Xp,   // [NCELL] float2
    float* __restrict__ util) {
    __shared__ float2 sm[NB];
    int row = blockIdx.x;
    int t = threadIdx.x;
    sm[t] = Xp[row * NB + t];
    __syncthreads();
    #pragma unroll
    for (int off = 1; off < NB; off <<= 1) {
        float2 cur = sm[t];
        float2 add = (t >= off) ? sm[t - off] : make_float2(0.f, 0.f);
        __syncthreads();
        cur.x += add.x; cur.y += add.y;
        sm[t] = cur;
        __syncthreads();
    }
    constexpr float invx = 1.f / (S * S * UNIT_H_CAP);
    constexpr float invy = 1.f / (S * S * UNIT_V_CAP);
    float2 r = sm[t];
    float u = fmaxf(r.x * invx, r.y * invy);
    util[row * NB + t] = fminf(fmaxf(u, 0.5f), 2.0f);
}

// K5: per-movable-node area = sum over <=3x3 bins of ox*util*oy
__global__ __launch_bounds__(256) void node_kernel(
    const float* __restrict__ pos,
    const float* __restrict__ nsx,
    const float* __restrict__ nsy,
    const float* __restrict__ util,
    float* __restrict__ out) {
    int m = blockIdx.x * blockDim.x + threadIdx.x;
    if (m >= NUM_MOVABLE) return;
    float x  = pos[m];
    float y  = pos[NUM_NODES + m];
    float xh = x + nsx[m];
    float yh = y + nsy[m];
    int ax = max(0,      (int)floorf(x  / S) - 1);
    int bx = min(NB - 1, (int)floorf(xh / S) + 1);
    int ay = max(0,      (int)floorf(y  / S) - 1);
    int by = min(NB - 1, (int)floorf(yh / S) + 1);
    float acc = 0.f;
    for (int i = ax; i <= bx; ++i) {
        float ov = fminf(edgef(i + 1), xh) - fmaxf(edgef(i), x);
        if (ov <= 0.f) continue;
        float inner = 0.f;
        for (int j = ay; j <= by; ++j) {
            float ovy = fminf(edgef(j + 1), yh) - fmaxf(edgef(j), y);
            if (ovy > 0.f) inner += ovy * util[i * NB + j];
        }
        acc += ov * inner;
    }
    out[m] = acc;
}

extern "C" void kernel_launch(void* const* d_in, const int* in_sizes, int n_in,
                              void* d_out, int out_size, void* d_ws, size_t ws_size,
                              hipStream_t stream) {
    const float* pos      = (const float*)d_in[0];
    const float* pin_pos  = (const float*)d_in[1];
    const float* nsx      = (const float*)d_in[2];
    const float* nsy      = (const float*)d_in[3];
    const float* nw       = (const float*)d_in[4];
    const int*   npstart  = (const int*)d_in[5];
    const int*   fnp      = (const int*)d_in[6];
    float*       out      = (float*)d_out;

    // ws layout (floats): Rc[NCHUNK*NFL] | Xp[NFL] | util[NCELL] | P[B*NFL]
    float* w    = (float*)d_ws;
    float* Rc   = w;                           w += NCHUNK * NFL;
    float* Xp   = w;                           w += NFL;
    float* util = w;                           w += NCELL;
    float* P    = w;

    size_t fixed = (size_t)(w - (float*)d_ws) * sizeof(float);
    int B = NDB;
    if (ws_size > fixed) {
        size_t fit = (ws_size - fixed) / ((size_t)NFL * sizeof(float));
        if ((size_t)B > fit) B = (int)fit;
    } else {
        B = 1;
    }
    if (B < 1) B = 1;

    (void)hipFuncSetAttribute((const void*)net_diff_kernel,
                              hipFuncAttributeMaxDynamicSharedMemorySize,
                              NFL * (int)sizeof(float));

    net_diff_kernel<<<B, TPB, NFL * sizeof(float), stream>>>(
        pin_pos, nw, npstart, fnp, P);
    {
        dim3 g(NFL / 4 / 256, NCHUNK);   // 32 x 8 blocks
        reduce_kernel<<<g, 256, 0, stream>>>(
            (const float4*)P, (float4*)Rc, B);
    }
    scan_x_kernel<<<NB, NB, 0, stream>>>(Rc, (float2*)Xp);
    scan_y_kernel<<<NB, NB, 0, stream>>>((const float2*)Xp, util);
    node_kernel<<<(NUM_MOVABLE + 255) / 256, 256, 0, stream>>>(
        pos, nsx, nsy, util, out);
}